// Round 3
// baseline (314.235 us; speedup 1.0000x reference)
//
#include <hip/hip_runtime.h>

// perm_inv_n: x[256,512,64] fp32 ->
//   per z (flat): cs[64] | gram[64x64] | ss[64] | cs^2[64] | (gram x cs)[64^3]
// Two kernels:
//   k_stats: 1 block/z, 512 threads -> cs, gram, h3, h4 (UNCHANGED from round 1,
//            held constant for attribution)
//   k_h5:    16 blocks/z, 256 threads. CHANGED: gram slab + cs staged in LDS once
//            (no global loads in the store loop), PLAIN dwordx4 stores (not NT) to
//            mimic the 6.4 TB/s fillBuffer behavior observed in rocprof.
#define Z_DIM 256
#define A_DIM 512
#define B_DIM 64
#define PER_Z 266432
#define GRAM_OFF 64
#define H3_OFF 4160
#define H4_OFF 4224
#define H5_OFF 4288
#define CHUNK 128

typedef float f4v __attribute__((ext_vector_type(4)));

__global__ __launch_bounds__(512) void k_stats(const float* __restrict__ x,
                                               float* __restrict__ out) {
    __shared__ float sx[2][CHUNK * B_DIM];  // 64 KB staging (one chunk per half)
    __shared__ float sg[B_DIM * B_DIM];     // 16 KB half-1 partial gram
    __shared__ float scs1[B_DIM];           // half-1 partial col sums

    const int z = blockIdx.x;
    const int t = threadIdx.x;
    const int half = t >> 8;   // 0 or 1
    const int u = t & 255;
    const int tb = u >> 4;     // 0..15 -> gram rows tb*4..tb*4+3
    const int tc = u & 15;     // 0..15 -> gram cols tc*4..tc*4+3

    const float* xz = x + (size_t)z * (A_DIM * B_DIM);
    float* oz = out + (size_t)z * PER_Z;

    float acc[4][4];
#pragma unroll
    for (int i = 0; i < 4; i++)
#pragma unroll
        for (int j = 0; j < 4; j++) acc[i][j] = 0.f;
    float cs_acc = 0.f;

    float* my_sx = sx[half];

    // Each half processes 2 chunks of 128 rows: half h takes chunks {h, h+2}.
    for (int c = 0; c < 2; c++) {
        const int a0 = (c * 2 + half) * CHUNK;
        const float4* src = (const float4*)(xz + a0 * B_DIM);
        float4* dst = (float4*)my_sx;
#pragma unroll
        for (int i = 0; i < 8; i++) dst[u + i * 256] = src[u + i * 256];
        __syncthreads();

        for (int a = 0; a < CHUNK; a++) {
            float4 bv = *(const float4*)&my_sx[a * B_DIM + tb * 4];
            float4 cv = *(const float4*)&my_sx[a * B_DIM + tc * 4];
            float bb[4] = {bv.x, bv.y, bv.z, bv.w};
            float cc[4] = {cv.x, cv.y, cv.z, cv.w};
#pragma unroll
            for (int i = 0; i < 4; i++)
#pragma unroll
                for (int j = 0; j < 4; j++)
                    acc[i][j] = fmaf(bb[i], cc[j], acc[i][j]);
        }
        if (u < B_DIM) {  // first wave of each half: partial column sums
#pragma unroll 4
            for (int a = 0; a < CHUNK; a++) cs_acc += my_sx[a * B_DIM + u];
        }
        __syncthreads();
    }

    // --- reduce the two halves, write h1..h4 ---
    if (half) {
#pragma unroll
        for (int i = 0; i < 4; i++) {
            float4 v = make_float4(acc[i][0], acc[i][1], acc[i][2], acc[i][3]);
            *(float4*)&sg[(tb * 4 + i) * B_DIM + tc * 4] = v;
        }
        if (u < B_DIM) scs1[u] = cs_acc;
    }
    __syncthreads();
    if (!half) {
#pragma unroll
        for (int i = 0; i < 4; i++) {
            float4 p = *(const float4*)&sg[(tb * 4 + i) * B_DIM + tc * 4];
            float vv[4] = {acc[i][0] + p.x, acc[i][1] + p.y,
                           acc[i][2] + p.z, acc[i][3] + p.w};
            *(float4*)&oz[GRAM_OFF + (size_t)(tb * 4 + i) * B_DIM + tc * 4] =
                make_float4(vv[0], vv[1], vv[2], vv[3]);           // h2
            if (tb == tc) oz[H3_OFF + tb * 4 + i] = vv[i];         // h3 = diag
        }
        if (u < B_DIM) {
            float c = cs_acc + scs1[u];
            oz[u] = c;                 // h1
            oz[H4_OFF + u] = c * c;    // h4
        }
    }
}

// h5[b][c][d] = gram[b*64+c] * cs[d].  grid = 256 z * 16 slabs, 256 threads.
// Slab s covers bc in [s*256, s*256+256): 64 KB contiguous stores per block.
// gram slab (1 KB) + cs (256 B) staged to LDS once -> the store loop has NO
// global loads on its critical path. Plain stores (the 6.4 TB/s fill uses plain).
__global__ __launch_bounds__(256) void k_h5(const float* __restrict__ outc,
                                            float* __restrict__ out) {
    __shared__ __align__(16) float sgr[256];
    __shared__ __align__(16) float scs[B_DIM];

    const int z = blockIdx.x >> 4;
    const int s = blockIdx.x & 15;
    const int t = threadIdx.x;

    const float* oz = outc + (size_t)z * PER_Z;
    sgr[t] = oz[GRAM_OFF + s * 256 + t];   // one coalesced 1 KB load
    if (t < B_DIM) scs[t] = oz[t];
    __syncthreads();

    const int dg = t & 15;   // d-group: d = dg*4 .. dg*4+3
    const int bq = t >> 4;   // 0..15
    const f4v c4 = *(const f4v*)&scs[dg * 4];

    f4v* o5 = (f4v*)(out + (size_t)z * PER_Z + H5_OFF);
    const size_t base = (size_t)s * 4096 + bq * 16 + dg;
#pragma unroll
    for (int i = 0; i < 16; i++) {
        const float g = sgr[bq + i * 16];   // LDS broadcast, ~free
        f4v v = {g * c4.x, g * c4.y, g * c4.z, g * c4.w};
        // per wave: 64 contiguous float4 = 1 KB aligned segment
        o5[base + (size_t)i * 256] = v;
    }
}

extern "C" void kernel_launch(void* const* d_in, const int* in_sizes, int n_in,
                              void* d_out, int out_size, void* d_ws, size_t ws_size,
                              hipStream_t stream) {
    const float* x = (const float*)d_in[0];
    float* out = (float*)d_out;
    k_stats<<<Z_DIM, 512, 0, stream>>>(x, out);
    k_h5<<<Z_DIM * 16, 256, 0, stream>>>(out, out);
}

// Round 4
// 308.514 us; speedup vs baseline: 1.0185x; 1.0185x over previous
//
#include <hip/hip_runtime.h>

// perm_inv_n: x[256,512,64] fp32 ->
//   per z (flat): cs[64] | gram[64x64] | ss[64] | cs^2[64] | (gram x cs)[64^3]
// Two kernels:
//   k_stats (REWRITTEN): 1 block/z, 512 threads. 8x8-per-lane register tile ->
//     one wave computes a full 64x64 partial gram over its 8 rows/chunk.
//     Inner loop: 4 ds_read_b128 per 64 FMA (was 2 per 16). Double-buffered
//     64-row chunks; loads issued before compute. In-LDS tree reduction of the
//     8 wave partials. cs accumulated by lanes 0-7 during the FMA loop.
//   k_h5 (UNCHANGED from round 3, held constant for attribution).
#define Z_DIM 256
#define A_DIM 512
#define B_DIM 64
#define PER_Z 266432
#define GRAM_OFF 64
#define H3_OFF 4160
#define H4_OFF 4224
#define H5_OFF 4288

typedef float f4v __attribute__((ext_vector_type(4)));

__device__ __forceinline__ void wave_store_tile(float* area, const float acc[8][8],
                                                int R, int C) {
#pragma unroll
    for (int i = 0; i < 8; i++) {
        *(float4*)&area[(R + i) * B_DIM + C] =
            make_float4(acc[i][0], acc[i][1], acc[i][2], acc[i][3]);
        *(float4*)&area[(R + i) * B_DIM + C + 4] =
            make_float4(acc[i][4], acc[i][5], acc[i][6], acc[i][7]);
    }
}

__device__ __forceinline__ void wave_add_tile(const float* area, float acc[8][8],
                                              int R, int C) {
#pragma unroll
    for (int i = 0; i < 8; i++) {
        float4 p0 = *(const float4*)&area[(R + i) * B_DIM + C];
        float4 p1 = *(const float4*)&area[(R + i) * B_DIM + C + 4];
        acc[i][0] += p0.x; acc[i][1] += p0.y; acc[i][2] += p0.z; acc[i][3] += p0.w;
        acc[i][4] += p1.x; acc[i][5] += p1.y; acc[i][6] += p1.z; acc[i][7] += p1.w;
    }
}

__global__ __launch_bounds__(512) void k_stats(const float* __restrict__ x,
                                               float* __restrict__ out) {
    __shared__ float sx[2][B_DIM * B_DIM];  // 32 KB: dbuf staging, then 2 reduce areas
    __shared__ float csred[8][B_DIM];       // 2 KB cs partials

    const int z = blockIdx.x;
    const int t = threadIdx.x;
    const int w = t >> 6;       // wave 0..7
    const int l = t & 63;
    const int R = (l >> 3) * 8; // gram row-tile base
    const int C = (l & 7) * 8;  // gram col-tile base

    const float* xz = x + (size_t)z * (A_DIM * B_DIM);
    float* oz = out + (size_t)z * PER_Z;

    float acc[8][8];
#pragma unroll
    for (int i = 0; i < 8; i++)
#pragma unroll
        for (int j = 0; j < 8; j++) acc[i][j] = 0.f;
    float csa[8];
#pragma unroll
    for (int j = 0; j < 8; j++) csa[j] = 0.f;

    // prologue: stage chunk 0 (64 rows = 16 KB = 1024 float4, 2 per thread)
    {
        const float4* src = (const float4*)xz;
        float4 r0 = src[t], r1 = src[t + 512];
        ((float4*)sx[0])[t] = r0;
        ((float4*)sx[0])[t + 512] = r1;
    }
    __syncthreads();

    for (int c = 0; c < 8; ++c) {
        const float* buf = sx[c & 1];
        float4 n0, n1;
        if (c < 7) {  // issue next chunk's loads BEFORE compute (latency hides)
            const float4* src = (const float4*)(xz + (size_t)(c + 1) * 64 * B_DIM);
            n0 = src[t];
            n1 = src[t + 512];
        }
        // wave w computes rows [w*8, w*8+8) of this chunk against full 64x64 tile
        const float* rbase = buf + (w * 8) * B_DIM;
#pragma unroll
        for (int k = 0; k < 8; ++k) {
            const float* row = rbase + k * B_DIM;
            float4 b0 = *(const float4*)(row + R);
            float4 b1 = *(const float4*)(row + R + 4);
            float4 c0 = *(const float4*)(row + C);
            float4 c1 = *(const float4*)(row + C + 4);
            float xb[8] = {b0.x, b0.y, b0.z, b0.w, b1.x, b1.y, b1.z, b1.w};
            float xc[8] = {c0.x, c0.y, c0.z, c0.w, c1.x, c1.y, c1.z, c1.w};
#pragma unroll
            for (int i = 0; i < 8; i++)
#pragma unroll
                for (int j = 0; j < 8; j++)
                    acc[i][j] = fmaf(xb[i], xc[j], acc[i][j]);
            if (l < 8) {  // lanes 0-7 (R==0): cs partial for cols l*8..l*8+7
#pragma unroll
                for (int j = 0; j < 8; j++) csa[j] += xc[j];
            }
        }
        if (c < 7) {  // write next chunk into the other buffer (no read conflict)
            float* nb = sx[(c + 1) & 1];
            ((float4*)nb)[t] = n0;
            ((float4*)nb)[t + 512] = n1;
        }
        __syncthreads();
    }

    // cs partials -> LDS (read by wave 0 at the end, after several barriers)
    if (l < 8) {
#pragma unroll
        for (int j = 0; j < 8; j++) csred[w][l * 8 + j] = csa[j];
    }

    // tree-reduce 8 wave partials using sx[0]/sx[1] as two 16 KB areas
    float* area0 = sx[0];
    float* area1 = sx[1];
    if (w == 4) wave_store_tile(area0, acc, R, C);
    if (w == 5) wave_store_tile(area1, acc, R, C);
    __syncthreads();
    if (w == 0) wave_add_tile(area0, acc, R, C);
    if (w == 1) wave_add_tile(area1, acc, R, C);
    __syncthreads();
    if (w == 6) wave_store_tile(area0, acc, R, C);
    if (w == 7) wave_store_tile(area1, acc, R, C);
    __syncthreads();
    if (w == 2) wave_add_tile(area0, acc, R, C);
    if (w == 3) wave_add_tile(area1, acc, R, C);
    __syncthreads();
    if (w == 2) wave_store_tile(area0, acc, R, C);
    if (w == 3) wave_store_tile(area1, acc, R, C);
    __syncthreads();
    if (w == 0) wave_add_tile(area0, acc, R, C);
    if (w == 1) wave_add_tile(area1, acc, R, C);
    __syncthreads();
    if (w == 1) wave_store_tile(area0, acc, R, C);
    __syncthreads();

    if (w == 0) {
        wave_add_tile(area0, acc, R, C);  // final gram tile in wave 0's registers
        // h2: gram
#pragma unroll
        for (int i = 0; i < 8; i++) {
            *(float4*)&oz[GRAM_OFF + (size_t)(R + i) * B_DIM + C] =
                make_float4(acc[i][0], acc[i][1], acc[i][2], acc[i][3]);
            *(float4*)&oz[GRAM_OFF + (size_t)(R + i) * B_DIM + C + 4] =
                make_float4(acc[i][4], acc[i][5], acc[i][6], acc[i][7]);
        }
        // h3: diagonal (lanes whose tile straddles the diagonal: R==C)
        if ((l >> 3) == (l & 7)) {
#pragma unroll
            for (int i = 0; i < 8; i++) oz[H3_OFF + R + i] = acc[i][i];
        }
        // h1/h4: cs = sum of the 8 per-wave partials
        float cs = 0.f;
#pragma unroll
        for (int ww = 0; ww < 8; ww++) cs += csred[ww][l];
        oz[l] = cs;
        oz[H4_OFF + l] = cs * cs;
    }
}

// h5[b][c][d] = gram[b*64+c] * cs[d].  grid = 256 z * 16 slabs, 256 threads.
// Slab s covers bc in [s*256, s*256+256): 64 KB contiguous stores per block.
// UNCHANGED from round 3.
__global__ __launch_bounds__(256) void k_h5(const float* __restrict__ outc,
                                            float* __restrict__ out) {
    __shared__ __align__(16) float sgr[256];
    __shared__ __align__(16) float scs[B_DIM];

    const int z = blockIdx.x >> 4;
    const int s = blockIdx.x & 15;
    const int t = threadIdx.x;

    const float* oz = outc + (size_t)z * PER_Z;
    sgr[t] = oz[GRAM_OFF + s * 256 + t];   // one coalesced 1 KB load
    if (t < B_DIM) scs[t] = oz[t];
    __syncthreads();

    const int dg = t & 15;   // d-group: d = dg*4 .. dg*4+3
    const int bq = t >> 4;   // 0..15
    const f4v c4 = *(const f4v*)&scs[dg * 4];

    f4v* o5 = (f4v*)(out + (size_t)z * PER_Z + H5_OFF);
    const size_t base = (size_t)s * 4096 + bq * 16 + dg;
#pragma unroll
    for (int i = 0; i < 16; i++) {
        const float g = sgr[bq + i * 16];   // LDS broadcast, ~free
        f4v v = {g * c4.x, g * c4.y, g * c4.z, g * c4.w};
        o5[base + (size_t)i * 256] = v;     // per wave: 1 KB contiguous segment
    }
}

extern "C" void kernel_launch(void* const* d_in, const int* in_sizes, int n_in,
                              void* d_out, int out_size, void* d_ws, size_t ws_size,
                              hipStream_t stream) {
    const float* x = (const float*)d_in[0];
    float* out = (float*)d_out;
    k_stats<<<Z_DIM, 512, 0, stream>>>(x, out);
    k_h5<<<Z_DIM * 16, 256, 0, stream>>>(out, out);
}